// Round 1
// baseline (450.630 us; speedup 1.0000x reference)
//
#include <hip/hip_runtime.h>
#include <hip/hip_bf16.h>
#include <cstdint>
#include <cstddef>

#define D_MODEL 1024
#define NHEADS 16
#define HD 64
#define NB 2
#define SL 2048
#define SEQ (NB*SL)      // 4096
#define NQKV (3*D_MODEL) // 3072

typedef __attribute__((ext_vector_type(8))) short short8;
typedef __attribute__((ext_vector_type(4))) float floatx4;
typedef unsigned short u16;

__device__ __forceinline__ u16 f2bf(float f) {
    union { float f; uint32_t u; } v; v.f = f;
    return (u16)((v.u + 0x7fffu + ((v.u >> 16) & 1u)) >> 16);
}

// ---------------- fp32 -> bf16 convert (vectorized x4) ----------------
__global__ __launch_bounds__(256) void cvt_kernel(const float* __restrict__ in,
                                                  u16* __restrict__ out, int n4) {
    int i = blockIdx.x * 256 + threadIdx.x;
    if (i >= n4) return;
    float4 f = ((const float4*)in)[i];
    ushort4 o;
    o.x = f2bf(f.x); o.y = f2bf(f.y); o.z = f2bf(f.z); o.w = f2bf(f.w);
    ((ushort4*)out)[i] = o;
}

// ---------------- shared 64x64-per-wave GEMM core: C = A * B^T ----------------
// A [M,1024] bf16 row-major, Bw [N,1024] bf16 row-major (K contiguous both).
// a-frag: A[m=l15][k=quad*8+j]; b-frag: B[n=l15][k=quad*8+j];
// D layout: col=lane&15, row=quad*4+reg (m89/m91 verified).
__device__ __forceinline__ void gemm64x64(const u16* __restrict__ A,
                                          const u16* __restrict__ Bw,
                                          int mbase, int nbase, floatx4 acc[4][4]) {
    const int lane = threadIdx.x & 63;
    const int l15 = lane & 15, quad = lane >> 4;
    #pragma unroll
    for (int i = 0; i < 4; i++)
        #pragma unroll
        for (int j = 0; j < 4; j++)
            acc[i][j] = (floatx4){0.f, 0.f, 0.f, 0.f};
    const u16* Ap = A + (size_t)(mbase + l15) * 1024 + quad * 8;
    const u16* Bp = Bw + (size_t)(nbase + l15) * 1024 + quad * 8;
    for (int k0 = 0; k0 < 1024; k0 += 32) {
        short8 af[4], bf[4];
        #pragma unroll
        for (int i = 0; i < 4; i++) af[i] = *(const short8*)(Ap + i * 16 * 1024 + k0);
        #pragma unroll
        for (int j = 0; j < 4; j++) bf[j] = *(const short8*)(Bp + j * 16 * 1024 + k0);
        #pragma unroll
        for (int i = 0; i < 4; i++)
            #pragma unroll
            for (int j = 0; j < 4; j++)
                acc[i][j] = __builtin_amdgcn_mfma_f32_16x16x32_bf16(af[i], bf[j], acc[i][j], 0, 0, 0);
    }
}

// ---------------- QKV GEMM: [4096,1024] x [3072,1024]^T + bias ----------------
// Epilogue: scatter to Q [BH][L][64] (x SCALE), K [BH][L][64], Vt [BH][64][L], all bf16.
__global__ __launch_bounds__(256) void qkv_gemm(const u16* __restrict__ xb,
                                                const u16* __restrict__ wb,
                                                const float* __restrict__ bias,
                                                u16* __restrict__ Qo, u16* __restrict__ Ko,
                                                u16* __restrict__ Vt) {
    const int wave = threadIdx.x >> 6;
    const int wr = wave >> 1, wc = wave & 1;
    const int mbase = blockIdx.y * 128 + wr * 64;
    const int nbase = blockIdx.x * 128 + wc * 64;
    floatx4 acc[4][4];
    gemm64x64(xb, wb, mbase, nbase, acc);
    const int lane = threadIdx.x & 63;
    const int l15 = lane & 15, quad = lane >> 4;
    #pragma unroll
    for (int j = 0; j < 4; j++) {
        int n = nbase + j * 16 + l15;
        float bv = bias[n];
        int which = n >> 10;        // block-uniform (128 | 1024)
        int within = n & 1023;
        int h = within >> 6, d = within & 63;
        #pragma unroll
        for (int i = 0; i < 4; i++) {
            #pragma unroll
            for (int r = 0; r < 4; r++) {
                int m = mbase + i * 16 + quad * 4 + r;
                int b = m >> 11, l = m & 2047;
                int bh = b * NHEADS + h;
                float v = acc[i][j][r] + bv;
                if (which == 0)      Qo[((size_t)bh * SL + l) * HD + d] = f2bf(v * 0.125f); // SCALE folded
                else if (which == 1) Ko[((size_t)bh * SL + l) * HD + d] = f2bf(v);
                else                 Vt[((size_t)bh * HD + d) * SL + l] = f2bf(v);
            }
        }
    }
}

// ---------------- Flash attention: one (bh, 64-q-row) block, 4 waves x 16 rows ----------------
__global__ __launch_bounds__(256) void flash_kernel(const u16* __restrict__ Q,
                                                    const u16* __restrict__ K,
                                                    const u16* __restrict__ V,
                                                    u16* __restrict__ AO) {
    __shared__ __align__(16) u16 pbuf[4][16][40]; // per-wave P tile [16 rows][32 keys], pad 40
    const int wave = threadIdx.x >> 6;
    const int lane = threadIdx.x & 63;
    const int l15 = lane & 15, quad = lane >> 4;
    const int bh = blockIdx.y;
    const int b = bh >> 4, h = bh & 15;
    const int qbase = blockIdx.x * 64 + wave * 16;
    const u16* Qp = Q + (size_t)bh * SL * HD;
    const u16* Kp = K + (size_t)bh * SL * HD;
    const u16* Vp = V + (size_t)bh * HD * SL;

    // Q fragments for this wave's 16 rows (kdim = 64 -> 2 ksteps), Q pre-scaled by 0.125
    short8 qf0 = *(const short8*)(Qp + (size_t)(qbase + l15) * HD + quad * 8);
    short8 qf1 = *(const short8*)(Qp + (size_t)(qbase + l15) * HD + 32 + quad * 8);

    floatx4 accO[4];
    #pragma unroll
    for (int d = 0; d < 4; d++) accO[d] = (floatx4){0.f, 0.f, 0.f, 0.f};
    float m_i[4], l_i[4];
    #pragma unroll
    for (int r = 0; r < 4; r++) { m_i[r] = -__builtin_inff(); l_i[r] = 0.f; }

    for (int kt = 0; kt < SL; kt += 32) {
        short8 kf0 = *(const short8*)(Kp + (size_t)(kt + l15) * HD + quad * 8);
        short8 kf1 = *(const short8*)(Kp + (size_t)(kt + l15) * HD + 32 + quad * 8);
        short8 kf2 = *(const short8*)(Kp + (size_t)(kt + 16 + l15) * HD + quad * 8);
        short8 kf3 = *(const short8*)(Kp + (size_t)(kt + 16 + l15) * HD + 32 + quad * 8);
        floatx4 s0 = (floatx4){0.f, 0.f, 0.f, 0.f};
        floatx4 s1 = (floatx4){0.f, 0.f, 0.f, 0.f};
        s0 = __builtin_amdgcn_mfma_f32_16x16x32_bf16(qf0, kf0, s0, 0, 0, 0);
        s0 = __builtin_amdgcn_mfma_f32_16x16x32_bf16(qf1, kf1, s0, 0, 0, 0);
        s1 = __builtin_amdgcn_mfma_f32_16x16x32_bf16(qf0, kf2, s1, 0, 0, 0);
        s1 = __builtin_amdgcn_mfma_f32_16x16x32_bf16(qf1, kf3, s1, 0, 0, 0);

        // online softmax per q-row (row = quad*4+r; 16 key-cols spread over 16 lanes)
        #pragma unroll
        for (int r = 0; r < 4; r++) {
            float mx = fmaxf(s0[r], s1[r]);
            #pragma unroll
            for (int off = 8; off >= 1; off >>= 1) mx = fmaxf(mx, __shfl_xor(mx, off, 16));
            float mnew = fmaxf(m_i[r], mx);
            float alpha = __expf(m_i[r] - mnew);
            m_i[r] = mnew;
            float p0 = __expf(s0[r] - mnew);
            float p1 = __expf(s1[r] - mnew);
            float rs = p0 + p1;
            #pragma unroll
            for (int off = 8; off >= 1; off >>= 1) rs += __shfl_xor(rs, off, 16);
            l_i[r] = l_i[r] * alpha + rs;
            #pragma unroll
            for (int d = 0; d < 4; d++) accO[d][r] *= alpha;
            pbuf[wave][quad * 4 + r][l15] = f2bf(p0);
            pbuf[wave][quad * 4 + r][16 + l15] = f2bf(p1);
        }
        // C-layout -> A-layout via per-wave LDS (intra-wave: DS ops in order, no barrier)
        short8 pf = *(const short8*)(&pbuf[wave][l15][quad * 8]);
        #pragma unroll
        for (int d = 0; d < 4; d++) {
            short8 vf = *(const short8*)(Vp + (size_t)(d * 16 + l15) * SL + kt + quad * 8);
            accO[d] = __builtin_amdgcn_mfma_f32_16x16x32_bf16(pf, vf, accO[d], 0, 0, 0);
        }
    }
    float inv[4];
    #pragma unroll
    for (int r = 0; r < 4; r++) inv[r] = 1.f / l_i[r];
    #pragma unroll
    for (int d = 0; d < 4; d++)
        #pragma unroll
        for (int r = 0; r < 4; r++) {
            int row = b * SL + qbase + quad * 4 + r;
            int col = h * HD + d * 16 + l15;
            AO[(size_t)row * D_MODEL + col] = f2bf(accO[d][r] * inv[r]);
        }
}

// ---------------- Output projection: [4096,1024] x [1024,1024]^T + bias -> fp32 ----------------
__global__ __launch_bounds__(256) void proj_gemm(const u16* __restrict__ ab,
                                                 const u16* __restrict__ wb,
                                                 const float* __restrict__ bias,
                                                 float* __restrict__ out) {
    const int wave = threadIdx.x >> 6;
    const int wr = wave >> 1, wc = wave & 1;
    const int mbase = blockIdx.y * 128 + wr * 64;
    const int nbase = blockIdx.x * 128 + wc * 64;
    floatx4 acc[4][4];
    gemm64x64(ab, wb, mbase, nbase, acc);
    const int lane = threadIdx.x & 63;
    const int l15 = lane & 15, quad = lane >> 4;
    #pragma unroll
    for (int j = 0; j < 4; j++) {
        int n = nbase + j * 16 + l15;
        float bv = bias[n];
        #pragma unroll
        for (int i = 0; i < 4; i++) {
            #pragma unroll
            for (int r = 0; r < 4; r++) {
                int m = mbase + i * 16 + quad * 4 + r;
                out[(size_t)m * D_MODEL + n] = acc[i][j][r] + bv;
            }
        }
    }
}

extern "C" void kernel_launch(void* const* d_in, const int* in_sizes, int n_in,
                              void* d_out, int out_size, void* d_ws, size_t ws_size,
                              hipStream_t stream) {
    const float* x      = (const float*)d_in[0];
    const float* qkv_w  = (const float*)d_in[1];
    const float* qkv_b  = (const float*)d_in[2];
    const float* proj_w = (const float*)d_in[3];
    const float* proj_b = (const float*)d_in[4];
    float* out = (float*)d_out;
    char* ws = (char*)d_ws;

    // workspace layout (bytes)
    u16* xb    = (u16*)(ws);             // x bf16        [4096,1024]   8 MB
    u16* wqkv  = (u16*)(ws + 8388608);   // qkv_w bf16    [3072,1024]   6 MB
    u16* wproj = (u16*)(ws + 14680064);  // proj_w bf16   [1024,1024]   2 MB
    u16* Qb    = (u16*)(ws + 16777216);  // Q bf16        [32][2048][64] 8 MB (pre-scaled)
    u16* Kb    = (u16*)(ws + 25165824);  // K bf16        [32][2048][64] 8 MB
    u16* Vt    = (u16*)(ws + 33554432);  // V^T bf16      [32][64][2048] 8 MB
    u16* AO    = (u16*)(ws + 41943040);  // attn out bf16 [4096,1024]    8 MB

    cvt_kernel<<<4096, 256, 0, stream>>>(x, xb, 4194304 / 4);
    cvt_kernel<<<3072, 256, 0, stream>>>(qkv_w, wqkv, 3145728 / 4);
    cvt_kernel<<<1024, 256, 0, stream>>>(proj_w, wproj, 1048576 / 4);
    qkv_gemm<<<dim3(NQKV / 128, SEQ / 128), 256, 0, stream>>>(xb, wqkv, qkv_b, Qb, Kb, Vt);
    flash_kernel<<<dim3(SL / 64, NB * NHEADS), 256, 0, stream>>>(Qb, Kb, Vt, AO);
    proj_gemm<<<dim3(D_MODEL / 128, SEQ / 128), 256, 0, stream>>>(AO, wproj, proj_b, out);
}